// Round 12
// baseline (427.485 us; speedup 1.0000x reference)
//
#include <hip/hip_runtime.h>
#include <hip/hip_bf16.h>

#define BB 4
#define SS 2048
#define DD 2048
#define HH 16
#define HDD 128

typedef __bf16 bf16x8_t __attribute__((ext_vector_type(8)));
typedef float f32x4 __attribute__((ext_vector_type(4)));
typedef float f32x16 __attribute__((ext_vector_type(16)));

static __device__ __forceinline__ unsigned short f2bf(float f) {
    union { float f; unsigned u; } v; v.f = f;
    unsigned r = v.u + 0x7fffu + ((v.u >> 16) & 1u);
    return (unsigned short)(r >> 16);
}

static __device__ __forceinline__ unsigned cvtpk_bf16(float lo, float hiv) {
    unsigned r;
    asm("v_cvt_pk_bf16_f32 %0, %1, %2" : "=v"(r) : "v"(lo), "v"(hiv));
    return r;
}

static __device__ __forceinline__ void pl32swap(unsigned& a, unsigned& b) {
    auto rr = __builtin_amdgcn_permlane32_swap((int)a, (int)b, false, false);
    a = (unsigned)rr[0];
    b = (unsigned)rr[1];
}

static __device__ __forceinline__ void gload_lds16(const void* g, void* lds) {
    __builtin_amdgcn_global_load_lds(
        (const __attribute__((address_space(1))) void*)g,
        (__attribute__((address_space(3))) void*)lds, 16, 0, 0);
}

// ---------------- convert x fp32 -> bf16 ----------------
__global__ void convert_x(const float* __restrict__ x, unsigned short* __restrict__ xb, int n) {
    int i = (blockIdx.x * blockDim.x + threadIdx.x) * 4;
    int stride = gridDim.x * blockDim.x * 4;
    for (; i < n; i += stride) {
        float4 v = *(const float4*)(x + i);
        ushort4 o;
        o.x = f2bf(v.x); o.y = f2bf(v.y); o.z = f2bf(v.z); o.w = f2bf(v.w);
        *(ushort4*)(xb + i) = o;
    }
}

// ---------------- transpose + convert weights: T[n][k] = W[k][n] ----------------
__global__ void transpose_w(const float* __restrict__ Wq, const float* __restrict__ Wk,
                            const float* __restrict__ Wv, const float* __restrict__ Wo,
                            unsigned short* __restrict__ WqkvT, unsigned short* __restrict__ WoT) {
    __shared__ float t[32][33];
    const int z = blockIdx.z;
    const float* W = (z == 0) ? Wq : (z == 1) ? Wk : (z == 2) ? Wv : Wo;
    unsigned short* T = (z < 3) ? (WqkvT + (size_t)z * DD * DD) : WoT;
    const int k0 = blockIdx.x * 32, n0 = blockIdx.y * 32;
    const int tx = threadIdx.x, ty = threadIdx.y;
#pragma unroll
    for (int i = 0; i < 4; ++i) {
        int r = ty + i * 8;
        t[r][tx] = W[(size_t)(k0 + r) * DD + n0 + tx];
    }
    __syncthreads();
#pragma unroll
    for (int i = 0; i < 4; ++i) {
        int r = ty + i * 8;
        T[(size_t)(n0 + r) * DD + k0 + tx] = f2bf(t[tx][r]);
    }
}

// ---------------- 256x256 GEMM, BK=64, 8 waves, per-phase interleave (R8 exact: best measured) --
// MODE 0: Q is pre-scaled by softmax scale*log2(e) at epilogue (free fp32 mul).
template <int MODE>
__global__ __launch_bounds__(512, 1) void gemm256(
    const unsigned short* __restrict__ A, const unsigned short* __restrict__ BT,
    unsigned short* __restrict__ outQ, unsigned short* __restrict__ outK,
    unsigned short* __restrict__ outV, float* __restrict__ outF,
    const float* __restrict__ bias) {
    __shared__ __attribute__((aligned(16))) char lds[131072];
    const int tid = threadIdx.x, l = tid & 63;
    const int w = tid >> 6;
    const int wr = w >> 2, wc = w & 3;
    const int nwg = gridDim.x * gridDim.y;
    int lin = blockIdx.y * gridDim.x + blockIdx.x;
    lin = (lin & 7) * (nwg >> 3) + (lin >> 3);
    const int m0 = (lin / gridDim.x) * 256;
    const int n0 = (lin % gridDim.x) * 256;

    f32x4 acc[8][4] = {};

    const int rowl = tid >> 3, c16s = tid & 7;
    const int sw16 = (c16s ^ (rowl & 7)) * 16;
    const char* aSrc[4];
    const char* bSrc[4];
#pragma unroll
    for (int rg = 0; rg < 4; ++rg) {
        aSrc[rg] = (const char*)A + ((size_t)(m0 + rg * 64 + rowl) * 2048) * 2 + sw16;
        bSrc[rg] = (const char*)BT + ((size_t)(n0 + rg * 64 + rowl) * 2048) * 2 + sw16;
    }
    const int dstOff = tid * 16;

    auto stage2 = [&](int slot, int off, int which) {
        char* sA = lds + slot * 32768;
        char* sB = lds + 65536 + slot * 32768;
        if (which == 0) { gload_lds16(bSrc[0] + off, sB + 0 * 8192 + dstOff); gload_lds16(bSrc[1] + off, sB + 1 * 8192 + dstOff); }
        else if (which == 1) { gload_lds16(bSrc[2] + off, sB + 2 * 8192 + dstOff); gload_lds16(bSrc[3] + off, sB + 3 * 8192 + dstOff); }
        else if (which == 2) { gload_lds16(aSrc[0] + off, sA + 0 * 8192 + dstOff); gload_lds16(aSrc[2] + off, sA + 2 * 8192 + dstOff); }
        else { gload_lds16(aSrc[1] + off, sA + 1 * 8192 + dstOff); gload_lds16(aSrc[3] + off, sA + 3 * 8192 + dstOff); }
    };

#pragma unroll
    for (int q = 0; q < 4; ++q) stage2(0, 0, q);
    asm volatile("s_waitcnt vmcnt(0)" ::: "memory");
    __builtin_amdgcn_s_barrier();

    const int lr = l & 15, hi4 = l >> 4;
    for (int t = 0; t < 32; ++t) {
        const int cur = t & 1, sl1 = cur ^ 1;
        const bool nlast = (t + 1 < 32);
        const int off1 = (t + 1) * 128;
        const char* As_ = lds + cur * 32768;
        const char* Bs_ = lds + 65536 + cur * 32768;
        bf16x8_t aa[4], bb[4];

        // ---- p0: (mh0, k0) ----
#pragma unroll
        for (int mq = 0; mq < 4; ++mq) {
            int row = wr * 128 + mq * 16 + lr;
            aa[mq] = *(const bf16x8_t*)(As_ + row * 128 + ((hi4) ^ (row & 7)) * 16);
        }
#pragma unroll
        for (int nq = 0; nq < 4; ++nq) {
            int col = wc * 64 + nq * 16 + lr;
            bb[nq] = *(const bf16x8_t*)(Bs_ + col * 128 + ((hi4) ^ (col & 7)) * 16);
        }
        if (nlast) stage2(sl1, off1, 0);
        __builtin_amdgcn_s_barrier();
        asm volatile("s_waitcnt lgkmcnt(0)");
        __builtin_amdgcn_s_setprio(1);
#pragma unroll
        for (int mq = 0; mq < 4; ++mq)
#pragma unroll
            for (int nq = 0; nq < 4; ++nq)
                acc[mq][nq] = __builtin_amdgcn_mfma_f32_16x16x32_bf16(aa[mq], bb[nq], acc[mq][nq], 0, 0, 0);
        __builtin_amdgcn_s_setprio(0);
        if (nlast) { asm volatile("s_waitcnt vmcnt(2)" ::: "memory"); }
        else       { asm volatile("s_waitcnt vmcnt(0)" ::: "memory"); }
        __builtin_amdgcn_s_barrier();

        // ---- p1: (mh1, k0), bb reused ----
#pragma unroll
        for (int mq = 0; mq < 4; ++mq) {
            int row = wr * 128 + 64 + mq * 16 + lr;
            aa[mq] = *(const bf16x8_t*)(As_ + row * 128 + ((hi4) ^ (row & 7)) * 16);
        }
        if (nlast) stage2(sl1, off1, 1);
        __builtin_amdgcn_s_barrier();
        asm volatile("s_waitcnt lgkmcnt(0)");
        __builtin_amdgcn_s_setprio(1);
#pragma unroll
        for (int mq = 0; mq < 4; ++mq)
#pragma unroll
            for (int nq = 0; nq < 4; ++nq)
                acc[4 + mq][nq] = __builtin_amdgcn_mfma_f32_16x16x32_bf16(aa[mq], bb[nq], acc[4 + mq][nq], 0, 0, 0);
        __builtin_amdgcn_s_setprio(0);
        __builtin_amdgcn_s_barrier();

        // ---- p2: (mh0, k1) ----
#pragma unroll
        for (int mq = 0; mq < 4; ++mq) {
            int row = wr * 128 + mq * 16 + lr;
            aa[mq] = *(const bf16x8_t*)(As_ + row * 128 + ((4 + hi4) ^ (row & 7)) * 16);
        }
#pragma unroll
        for (int nq = 0; nq < 4; ++nq) {
            int col = wc * 64 + nq * 16 + lr;
            bb[nq] = *(const bf16x8_t*)(Bs_ + col * 128 + ((4 + hi4) ^ (col & 7)) * 16);
        }
        if (nlast) stage2(sl1, off1, 2);
        __builtin_amdgcn_s_barrier();
        asm volatile("s_waitcnt lgkmcnt(0)");
        __builtin_amdgcn_s_setprio(1);
#pragma unroll
        for (int mq = 0; mq < 4; ++mq)
#pragma unroll
            for (int nq = 0; nq < 4; ++nq)
                acc[mq][nq] = __builtin_amdgcn_mfma_f32_16x16x32_bf16(aa[mq], bb[nq], acc[mq][nq], 0, 0, 0);
        __builtin_amdgcn_s_setprio(0);
        __builtin_amdgcn_s_barrier();

        // ---- p3: (mh1, k1), bb reused ----
#pragma unroll
        for (int mq = 0; mq < 4; ++mq) {
            int row = wr * 128 + 64 + mq * 16 + lr;
            aa[mq] = *(const bf16x8_t*)(As_ + row * 128 + ((4 + hi4) ^ (row & 7)) * 16);
        }
        if (nlast) stage2(sl1, off1, 3);
        __builtin_amdgcn_s_barrier();
        asm volatile("s_waitcnt lgkmcnt(0)");
        __builtin_amdgcn_s_setprio(1);
#pragma unroll
        for (int mq = 0; mq < 4; ++mq)
#pragma unroll
            for (int nq = 0; nq < 4; ++nq)
                acc[4 + mq][nq] = __builtin_amdgcn_mfma_f32_16x16x32_bf16(aa[mq], bb[nq], acc[4 + mq][nq], 0, 0, 0);
        __builtin_amdgcn_s_setprio(0);
        if (nlast) { asm volatile("s_waitcnt vmcnt(2)" ::: "memory"); }
        __builtin_amdgcn_s_barrier();
    }

    const int rbase = m0 + wr * 128 + (hi4 << 2);
    const int cbase = n0 + wc * 64 + lr;
    if (MODE == 0) {
        const float QSCALE = 0.08838834764831845f * 1.4426950408889634f;
#pragma unroll
        for (int nq = 0; nq < 4; ++nq) {
            int col = cbase + nq * 16;
            int mat = col >> 11;
            int nn = col & 2047;
            int h = nn >> 7, hd = nn & 127;
            if (mat == 2) {
#pragma unroll
                for (int i = 0; i < 8; ++i) {
                    int row = rbase + i * 16;
                    int b = row >> 11, s = row & 2047;
                    ushort4 pk;
                    pk.x = f2bf(acc[i][nq][0]); pk.y = f2bf(acc[i][nq][1]);
                    pk.z = f2bf(acc[i][nq][2]); pk.w = f2bf(acc[i][nq][3]);
                    *(ushort4*)(outV + ((size_t)(b * HH + h) * HDD + hd) * SS + s) = pk;
                }
            } else {
                unsigned short* outp = mat ? outK : outQ;
                const float sc = mat ? 1.f : QSCALE;
#pragma unroll
                for (int i = 0; i < 8; ++i) {
#pragma unroll
                    for (int r = 0; r < 4; ++r) {
                        int row = rbase + i * 16 + r;
                        int b = row >> 11, s = row & 2047;
                        outp[((size_t)(b * HH + h) * SS + s) * HDD + hd] = f2bf(acc[i][nq][r] * sc);
                    }
                }
            }
        }
    } else {
#pragma unroll
        for (int nq = 0; nq < 4; ++nq) {
            int col = cbase + nq * 16;
            float bv = bias[col];
#pragma unroll
            for (int i = 0; i < 8; ++i) {
#pragma unroll
                for (int r = 0; r < 4; ++r) {
                    int row = rbase + i * 16 + r;
                    outF[(size_t)row * DD + col] = acc[i][nq][r] + bv;
                }
            }
        }
    }
}

// ---------------- flash attention: 4 warps x 32 q-rows, KVBLK=64, paired q-tiles --------------
// Counted-vmcnt schedule (no vmcnt(0) drain in steady state):
//   per tile: issue K(kt+1)x4 then V(kt+1)x4; QK^T+softmax on K(kt);
//   vmcnt(8)+bar (own V(kt) landed -> globally landed); PV on V(kt);
//   vmcnt(4)+bar (own K(kt+1) landed). Q is pre-scaled in the QKV GEMM.
__global__ __launch_bounds__(256, 2) void attn_kernel(
    const unsigned short* __restrict__ Q, const unsigned short* __restrict__ K,
    const unsigned short* __restrict__ VT, unsigned short* __restrict__ ctx) {
    __shared__ __attribute__((aligned(16))) unsigned short Ks[2][64 * 128];
    __shared__ __attribute__((aligned(16))) unsigned short Vs[2][128 * 64];
    __shared__ float Al[4][32];
    const int tid = threadIdx.x, w = tid >> 6, l = tid & 63;
    const int hi = l >> 5, l31 = l & 31;
    const int hb = hi * 16;
    const int swzK = (l31 & 15) << 4;
    const int swzV = (l31 & 7) << 4;
    const int p = blockIdx.x, h = blockIdx.y, b = blockIdx.z;
    const int bh = b * HH + h;

    const unsigned short* Qbh = Q + (size_t)bh * SS * HDD;
    const char* Kbh = (const char*)(K + (size_t)bh * SS * HDD);
    const char* Vbh = (const char*)(VT + (size_t)bh * HDD * SS);

    const char* kbase[4];
    const char* vbase[4];
#pragma unroll
    for (int i = 0; i < 4; ++i) {
        int cp = (i * 256 + tid) * 16;
        int krow = cp >> 8, kcb = cp & 255;
        kbase[i] = Kbh + (size_t)krow * 256 + (kcb ^ ((krow & 15) << 4));
        int vrow = cp >> 7, vcb = cp & 127;
        vbase[i] = Vbh + (size_t)vrow * (SS * 2) + (vcb ^ ((vrow & 7) << 4));
    }

    auto stageK = [&](int buf, int kv0) {
#pragma unroll
        for (int i = 0; i < 4; ++i) {
            int cp = (i * 256 + tid) * 16;
            gload_lds16(kbase[i] + (size_t)kv0 * 256, (char*)&Ks[buf][0] + cp);
        }
    };
    auto stageV = [&](int buf, int kv0) {
#pragma unroll
        for (int i = 0; i < 4; ++i) {
            int cp = (i * 256 + tid) * 16;
            gload_lds16(vbase[i] + (size_t)kv0 * 2, (char*)&Vs[buf][0] + cp);
        }
    };

    for (int pass = 0; pass < 2; ++pass) {
        const int qt = pass ? p : 15 - p;
        const int q0w = qt * 128 + w * 32;
        const int qabs = q0w + l31;
        const int nkv = 2 * qt + 2;

        bf16x8_t qf[8];
#pragma unroll
        for (int ds = 0; ds < 8; ++ds)
            qf[ds] = *(const bf16x8_t*)(Qbh + (size_t)qabs * HDD + ds * 16 + hi * 8);

        float m_r = -1e30f, l_r = 0.f;
        f32x16 o0 = {}, o1 = {}, o2 = {}, o3 = {};

        int buf = 0;
        stageK(0, 0);
        stageV(0, 0);
        asm volatile("s_waitcnt vmcnt(4)" ::: "memory");  // K(0) landed (own; all waves do same)
        __builtin_amdgcn_s_barrier();

        for (int kt = 0; kt < nkv; ++kt) {
            const int kv0 = kt * 64;
            const bool nlast = (kt + 1 < nkv);
            if (nlast) { stageK(buf ^ 1, kv0 + 64); stageV(buf ^ 1, kv0 + 64); }

            const bool active = (kv0 <= q0w + 31);
            const char* Kb = (const char*)&Ks[buf][0];
            const char* Vb = (const char*)&Vs[buf][0];
            f32x16 s0, s1;
            bf16x8_t pa[4];
            if (active) {
                s0 = (f32x16){}; s1 = (f32x16){};
                {
                    bf16x8_t kf[8];
                    const int rb = l31 * 256;
#pragma unroll
                    for (int ds = 0; ds < 8; ++ds)
                        kf[ds] = *(const bf16x8_t*)(Kb + rb + ((ds * 32 + hb) ^ swzK));
                    __builtin_amdgcn_s_setprio(1);
#pragma unroll
                    for (int ds = 0; ds < 8; ++ds)
                        s0 = __builtin_amdgcn_mfma_f32_32x32x16_bf16(kf[ds], qf[ds], s0, 0, 0, 0);
                    __builtin_amdgcn_s_setprio(0);
#pragma unroll
                    for (int ds = 0; ds < 8; ++ds)
                        kf[ds] = *(const bf16x8_t*)(Kb + rb + 32 * 256 + ((ds * 32 + hb) ^ swzK));
                    __builtin_amdgcn_s_setprio(1);
#pragma unroll
                    for (int ds = 0; ds < 8; ++ds)
                        s1 = __builtin_amdgcn_mfma_f32_32x32x16_bf16(kf[ds], qf[ds], s1, 0, 0, 0);
                    __builtin_amdgcn_s_setprio(0);
                }

                // causal mask only (scale folded into Q)
                if (kv0 + 63 > q0w) {
                    const int qrel = qabs - kv0;
#pragma unroll
                    for (int r = 0; r < 16; ++r) {
                        const int kl = (r & 3) + 8 * (r >> 2) + 4 * hi;
                        if (kl > qrel) s0[r] = -1e30f;
                        if (kl + 32 > qrel) s1[r] = -1e30f;
                    }
                }

                float mx = s0[0];
#pragma unroll
                for (int r = 1; r < 16; ++r) mx = fmaxf(mx, s0[r]);
#pragma unroll
                for (int r = 0; r < 16; ++r) mx = fmaxf(mx, s1[r]);
                {
                    unsigned mu = __float_as_uint(mx), mu2 = mu;
                    pl32swap(mu, mu2);
                    mx = fmaxf(__uint_as_float(mu), __uint_as_float(mu2));
                }

                if (__any(mx - m_r > 8.f)) {
                    float mnew = fmaxf(m_r, mx);
                    float alpha = exp2f(m_r - mnew);
                    m_r = mnew;
                    l_r *= alpha;
                    Al[w][l31] = alpha;
#pragma unroll
                    for (int r = 0; r < 16; ++r) {
                        float ar = Al[w][(r & 3) + 8 * (r >> 2) + 4 * hi];
                        o0[r] *= ar; o1[r] *= ar; o2[r] *= ar; o3[r] *= ar;
                    }
                }

                float ps = 0.f;
#pragma unroll
                for (int r = 0; r < 16; ++r) { s0[r] = exp2f(s0[r] - m_r); ps += s0[r]; }
#pragma unroll
                for (int r = 0; r < 16; ++r) { s1[r] = exp2f(s1[r] - m_r); ps += s1[r]; }
                {
                    unsigned pu = __float_as_uint(ps), pu2 = pu;
                    pl32swap(pu, pu2);
                    l_r += __uint_as_float(pu) + __uint_as_float(pu2);
                }

                {
                    union { unsigned u[4]; bf16x8_t v; } uu;
#define MK_PA(SV, BASE, OUT)                                     \
                    {                                            \
                        unsigned X0 = cvtpk_bf16(SV[BASE + 0], SV[BASE + 1]); \
                        unsigned Y0 = cvtpk_bf16(SV[BASE + 4], SV[BASE + 5]); \
                        pl32swap(X0, Y0);                        \
                        unsigned X1 = cvtpk_bf16(SV[BASE + 2], SV[BASE + 3]); \
                        unsigned Y1 = cvtpk_bf16(SV[BASE + 6], SV[BASE + 7]); \
                        pl32swap(X1, Y1);                        \
                        uu.u[0] = X0; uu.u[1] = X1; uu.u[2] = Y0; uu.u[3] = Y1; \
                        OUT = uu.v;                              \
                    }
                    MK_PA(s0, 0, pa[0]);
                    MK_PA(s0, 8, pa[1]);
                    MK_PA(s1, 0, pa[2]);
                    MK_PA(s1, 8, pa[3]);
#undef MK_PA
                }
            }

            // V(kt) landed (own; every wave waits before barrier -> global)
            if (nlast) { asm volatile("s_waitcnt vmcnt(8)" ::: "memory"); }
            else       { asm volatile("s_waitcnt vmcnt(0)" ::: "memory"); }
            __builtin_amdgcn_s_barrier();

            if (active) {
#pragma unroll
                for (int ks = 0; ks < 4; ++ks) {
                    bf16x8_t vf[4];
#pragma unroll
                    for (int dsub = 0; dsub < 4; ++dsub)
                        vf[dsub] = *(const bf16x8_t*)(Vb + (dsub * 32 + l31) * 128 + ((ks * 32 + hb) ^ swzV));
                    __builtin_amdgcn_s_setprio(1);
                    o0 = __builtin_amdgcn_mfma_f32_32x32x16_bf16(pa[ks], vf[0], o0, 0, 0, 0);
                    o1 = __builtin_amdgcn_mfma_f32_32x32x16_bf16(pa[ks], vf[1], o1, 0, 0, 0);
                    o2 = __builtin_amdgcn_mfma_f32_32x32x16_bf16(pa[ks], vf[2], o2, 0, 0, 0);
                    o3 = __builtin_amdgcn_mfma_f32_32x32x16_bf16(pa[ks], vf[3], o3, 0, 0, 0);
                    __builtin_amdgcn_s_setprio(0);
                }
            }

            // K(kt+1) landed; also WAR fence: all reads of buf done before next stage into buf
            if (nlast) { asm volatile("s_waitcnt vmcnt(4)" ::: "memory"); }
            __builtin_amdgcn_s_barrier();
            buf ^= 1;
        }

        Al[w][l31] = 1.f / l_r;
        unsigned short* cb_ = ctx + (size_t)b * SS * DD + (size_t)h * HDD;
#pragma unroll
        for (int r = 0; r < 16; ++r) {
            const int ql = (r & 3) + 8 * (r >> 2) + 4 * hi;
            float inv = Al[w][ql];
            const size_t rowoff = (size_t)(q0w + ql) * DD;
            cb_[rowoff + 0 * 32 + l31] = f2bf(o0[r] * inv);
            cb_[rowoff + 1 * 32 + l31] = f2bf(o1[r] * inv);
            cb_[rowoff + 2 * 32 + l31] = f2bf(o2[r] * inv);
            cb_[rowoff + 3 * 32 + l31] = f2bf(o3[r] * inv);
        }
        __syncthreads();  // pass boundary: next pass stages into buffer 0
    }
}

extern "C" void kernel_launch(void* const* d_in, const int* in_sizes, int n_in,
                              void* d_out, int out_size, void* d_ws, size_t ws_size,
                              hipStream_t stream) {
    (void)in_sizes; (void)n_in; (void)out_size; (void)ws_size;
    const float* x  = (const float*)d_in[0];
    const float* Wq = (const float*)d_in[1];
    const float* Wk = (const float*)d_in[2];
    const float* Wv = (const float*)d_in[3];
    const float* Wo = (const float*)d_in[4];
    const float* bo = (const float*)d_in[5];

    char* ws = (char*)d_ws;
    unsigned short* xb    = (unsigned short*)(ws);
    unsigned short* WqkvT = (unsigned short*)(ws + (32u << 20));
    unsigned short* WoT   = (unsigned short*)(ws + (56u << 20));
    unsigned short* Qb    = (unsigned short*)(ws + (64u << 20));
    unsigned short* Kb    = (unsigned short*)(ws + (96u << 20));
    unsigned short* VTb   = (unsigned short*)(ws + (160u << 20));
    unsigned short* ctx   = xb;  // xb dead after QKV GEMM

    convert_x<<<4096, 256, 0, stream>>>(x, xb, BB * SS * DD);
    transpose_w<<<dim3(64, 64, 4), dim3(32, 8), 0, stream>>>(Wq, Wk, Wv, Wo, WqkvT, WoT);
    gemm256<0><<<dim3(24, 32), 512, 0, stream>>>(xb, WqkvT, Qb, Kb, VTb, nullptr, nullptr);
    attn_kernel<<<dim3(8, HH, BB), 256, 0, stream>>>(Qb, Kb, VTb, ctx);
    gemm256<1><<<dim3(8, 32), 512, 0, stream>>>(ctx, WoT, nullptr, nullptr, nullptr, (float*)d_out, bo);
}

// Round 13
// 426.797 us; speedup vs baseline: 1.0016x; 1.0016x over previous
//
#include <hip/hip_runtime.h>
#include <hip/hip_bf16.h>

#define BB 4
#define SS 2048
#define DD 2048
#define HH 16
#define HDD 128

typedef __bf16 bf16x8_t __attribute__((ext_vector_type(8)));
typedef float f32x4 __attribute__((ext_vector_type(4)));
typedef float f32x16 __attribute__((ext_vector_type(16)));

static __device__ __forceinline__ unsigned short f2bf(float f) {
    union { float f; unsigned u; } v; v.f = f;
    unsigned r = v.u + 0x7fffu + ((v.u >> 16) & 1u);
    return (unsigned short)(r >> 16);
}

static __device__ __forceinline__ unsigned cvtpk_bf16(float lo, float hiv) {
    unsigned r;
    asm("v_cvt_pk_bf16_f32 %0, %1, %2" : "=v"(r) : "v"(lo), "v"(hiv));
    return r;
}

static __device__ __forceinline__ void pl32swap(unsigned& a, unsigned& b) {
    auto rr = __builtin_amdgcn_permlane32_swap((int)a, (int)b, false, false);
    a = (unsigned)rr[0];
    b = (unsigned)rr[1];
}

static __device__ __forceinline__ void gload_lds16(const void* g, void* lds) {
    __builtin_amdgcn_global_load_lds(
        (const __attribute__((address_space(1))) void*)g,
        (__attribute__((address_space(3))) void*)lds, 16, 0, 0);
}

// ---------------- convert x fp32 -> bf16 ----------------
__global__ void convert_x(const float* __restrict__ x, unsigned short* __restrict__ xb, int n) {
    int i = (blockIdx.x * blockDim.x + threadIdx.x) * 4;
    int stride = gridDim.x * blockDim.x * 4;
    for (; i < n; i += stride) {
        float4 v = *(const float4*)(x + i);
        ushort4 o;
        o.x = f2bf(v.x); o.y = f2bf(v.y); o.z = f2bf(v.z); o.w = f2bf(v.w);
        *(ushort4*)(xb + i) = o;
    }
}

// ---------------- transpose + convert weights: T[n][k] = W[k][n] ----------------
__global__ void transpose_w(const float* __restrict__ Wq, const float* __restrict__ Wk,
                            const float* __restrict__ Wv, const float* __restrict__ Wo,
                            unsigned short* __restrict__ WqkvT, unsigned short* __restrict__ WoT) {
    __shared__ float t[32][33];
    const int z = blockIdx.z;
    const float* W = (z == 0) ? Wq : (z == 1) ? Wk : (z == 2) ? Wv : Wo;
    unsigned short* T = (z < 3) ? (WqkvT + (size_t)z * DD * DD) : WoT;
    const int k0 = blockIdx.x * 32, n0 = blockIdx.y * 32;
    const int tx = threadIdx.x, ty = threadIdx.y;
#pragma unroll
    for (int i = 0; i < 4; ++i) {
        int r = ty + i * 8;
        t[r][tx] = W[(size_t)(k0 + r) * DD + n0 + tx];
    }
    __syncthreads();
#pragma unroll
    for (int i = 0; i < 4; ++i) {
        int r = ty + i * 8;
        T[(size_t)(n0 + r) * DD + k0 + tx] = f2bf(t[tx][r]);
    }
}

// ---------------- 256x256 GEMM, BK=64, 8 waves, per-phase interleave (R8 exact: best measured) --
// MODE 0: Q is pre-scaled by softmax scale*log2(e) at epilogue (free fp32 mul).
template <int MODE>
__global__ __launch_bounds__(512, 1) void gemm256(
    const unsigned short* __restrict__ A, const unsigned short* __restrict__ BT,
    unsigned short* __restrict__ outQ, unsigned short* __restrict__ outK,
    unsigned short* __restrict__ outV, float* __restrict__ outF,
    const float* __restrict__ bias) {
    __shared__ __attribute__((aligned(16))) char lds[131072];
    const int tid = threadIdx.x, l = tid & 63;
    const int w = tid >> 6;
    const int wr = w >> 2, wc = w & 3;
    const int nwg = gridDim.x * gridDim.y;
    int lin = blockIdx.y * gridDim.x + blockIdx.x;
    lin = (lin & 7) * (nwg >> 3) + (lin >> 3);
    const int m0 = (lin / gridDim.x) * 256;
    const int n0 = (lin % gridDim.x) * 256;

    f32x4 acc[8][4] = {};

    const int rowl = tid >> 3, c16s = tid & 7;
    const int sw16 = (c16s ^ (rowl & 7)) * 16;
    const char* aSrc[4];
    const char* bSrc[4];
#pragma unroll
    for (int rg = 0; rg < 4; ++rg) {
        aSrc[rg] = (const char*)A + ((size_t)(m0 + rg * 64 + rowl) * 2048) * 2 + sw16;
        bSrc[rg] = (const char*)BT + ((size_t)(n0 + rg * 64 + rowl) * 2048) * 2 + sw16;
    }
    const int dstOff = tid * 16;

    auto stage2 = [&](int slot, int off, int which) {
        char* sA = lds + slot * 32768;
        char* sB = lds + 65536 + slot * 32768;
        if (which == 0) { gload_lds16(bSrc[0] + off, sB + 0 * 8192 + dstOff); gload_lds16(bSrc[1] + off, sB + 1 * 8192 + dstOff); }
        else if (which == 1) { gload_lds16(bSrc[2] + off, sB + 2 * 8192 + dstOff); gload_lds16(bSrc[3] + off, sB + 3 * 8192 + dstOff); }
        else if (which == 2) { gload_lds16(aSrc[0] + off, sA + 0 * 8192 + dstOff); gload_lds16(aSrc[2] + off, sA + 2 * 8192 + dstOff); }
        else { gload_lds16(aSrc[1] + off, sA + 1 * 8192 + dstOff); gload_lds16(aSrc[3] + off, sA + 3 * 8192 + dstOff); }
    };

#pragma unroll
    for (int q = 0; q < 4; ++q) stage2(0, 0, q);
    asm volatile("s_waitcnt vmcnt(0)" ::: "memory");
    __builtin_amdgcn_s_barrier();

    const int lr = l & 15, hi4 = l >> 4;
    for (int t = 0; t < 32; ++t) {
        const int cur = t & 1, sl1 = cur ^ 1;
        const bool nlast = (t + 1 < 32);
        const int off1 = (t + 1) * 128;
        const char* As_ = lds + cur * 32768;
        const char* Bs_ = lds + 65536 + cur * 32768;
        bf16x8_t aa[4], bb[4];

        // ---- p0: (mh0, k0) ----
#pragma unroll
        for (int mq = 0; mq < 4; ++mq) {
            int row = wr * 128 + mq * 16 + lr;
            aa[mq] = *(const bf16x8_t*)(As_ + row * 128 + ((hi4) ^ (row & 7)) * 16);
        }
#pragma unroll
        for (int nq = 0; nq < 4; ++nq) {
            int col = wc * 64 + nq * 16 + lr;
            bb[nq] = *(const bf16x8_t*)(Bs_ + col * 128 + ((hi4) ^ (col & 7)) * 16);
        }
        if (nlast) stage2(sl1, off1, 0);
        __builtin_amdgcn_s_barrier();
        asm volatile("s_waitcnt lgkmcnt(0)");
        __builtin_amdgcn_s_setprio(1);
#pragma unroll
        for (int mq = 0; mq < 4; ++mq)
#pragma unroll
            for (int nq = 0; nq < 4; ++nq)
                acc[mq][nq] = __builtin_amdgcn_mfma_f32_16x16x32_bf16(aa[mq], bb[nq], acc[mq][nq], 0, 0, 0);
        __builtin_amdgcn_s_setprio(0);
        if (nlast) { asm volatile("s_waitcnt vmcnt(2)" ::: "memory"); }
        else       { asm volatile("s_waitcnt vmcnt(0)" ::: "memory"); }
        __builtin_amdgcn_s_barrier();

        // ---- p1: (mh1, k0), bb reused ----
#pragma unroll
        for (int mq = 0; mq < 4; ++mq) {
            int row = wr * 128 + 64 + mq * 16 + lr;
            aa[mq] = *(const bf16x8_t*)(As_ + row * 128 + ((hi4) ^ (row & 7)) * 16);
        }
        if (nlast) stage2(sl1, off1, 1);
        __builtin_amdgcn_s_barrier();
        asm volatile("s_waitcnt lgkmcnt(0)");
        __builtin_amdgcn_s_setprio(1);
#pragma unroll
        for (int mq = 0; mq < 4; ++mq)
#pragma unroll
            for (int nq = 0; nq < 4; ++nq)
                acc[4 + mq][nq] = __builtin_amdgcn_mfma_f32_16x16x32_bf16(aa[mq], bb[nq], acc[4 + mq][nq], 0, 0, 0);
        __builtin_amdgcn_s_setprio(0);
        __builtin_amdgcn_s_barrier();

        // ---- p2: (mh0, k1) ----
#pragma unroll
        for (int mq = 0; mq < 4; ++mq) {
            int row = wr * 128 + mq * 16 + lr;
            aa[mq] = *(const bf16x8_t*)(As_ + row * 128 + ((4 + hi4) ^ (row & 7)) * 16);
        }
#pragma unroll
        for (int nq = 0; nq < 4; ++nq) {
            int col = wc * 64 + nq * 16 + lr;
            bb[nq] = *(const bf16x8_t*)(Bs_ + col * 128 + ((4 + hi4) ^ (col & 7)) * 16);
        }
        if (nlast) stage2(sl1, off1, 2);
        __builtin_amdgcn_s_barrier();
        asm volatile("s_waitcnt lgkmcnt(0)");
        __builtin_amdgcn_s_setprio(1);
#pragma unroll
        for (int mq = 0; mq < 4; ++mq)
#pragma unroll
            for (int nq = 0; nq < 4; ++nq)
                acc[mq][nq] = __builtin_amdgcn_mfma_f32_16x16x32_bf16(aa[mq], bb[nq], acc[mq][nq], 0, 0, 0);
        __builtin_amdgcn_s_setprio(0);
        __builtin_amdgcn_s_barrier();

        // ---- p3: (mh1, k1), bb reused ----
#pragma unroll
        for (int mq = 0; mq < 4; ++mq) {
            int row = wr * 128 + 64 + mq * 16 + lr;
            aa[mq] = *(const bf16x8_t*)(As_ + row * 128 + ((4 + hi4) ^ (row & 7)) * 16);
        }
        if (nlast) stage2(sl1, off1, 3);
        __builtin_amdgcn_s_barrier();
        asm volatile("s_waitcnt lgkmcnt(0)");
        __builtin_amdgcn_s_setprio(1);
#pragma unroll
        for (int mq = 0; mq < 4; ++mq)
#pragma unroll
            for (int nq = 0; nq < 4; ++nq)
                acc[4 + mq][nq] = __builtin_amdgcn_mfma_f32_16x16x32_bf16(aa[mq], bb[nq], acc[4 + mq][nq], 0, 0, 0);
        __builtin_amdgcn_s_setprio(0);
        if (nlast) { asm volatile("s_waitcnt vmcnt(2)" ::: "memory"); }
        __builtin_amdgcn_s_barrier();
    }

    const int rbase = m0 + wr * 128 + (hi4 << 2);
    const int cbase = n0 + wc * 64 + lr;
    if (MODE == 0) {
        const float QSCALE = 0.08838834764831845f * 1.4426950408889634f;
#pragma unroll
        for (int nq = 0; nq < 4; ++nq) {
            int col = cbase + nq * 16;
            int mat = col >> 11;
            int nn = col & 2047;
            int h = nn >> 7, hd = nn & 127;
            if (mat == 2) {
#pragma unroll
                for (int i = 0; i < 8; ++i) {
                    int row = rbase + i * 16;
                    int b = row >> 11, s = row & 2047;
                    ushort4 pk;
                    pk.x = f2bf(acc[i][nq][0]); pk.y = f2bf(acc[i][nq][1]);
                    pk.z = f2bf(acc[i][nq][2]); pk.w = f2bf(acc[i][nq][3]);
                    *(ushort4*)(outV + ((size_t)(b * HH + h) * HDD + hd) * SS + s) = pk;
                }
            } else {
                unsigned short* outp = mat ? outK : outQ;
                const float sc = mat ? 1.f : QSCALE;
#pragma unroll
                for (int i = 0; i < 8; ++i) {
#pragma unroll
                    for (int r = 0; r < 4; ++r) {
                        int row = rbase + i * 16 + r;
                        int b = row >> 11, s = row & 2047;
                        outp[((size_t)(b * HH + h) * SS + s) * HDD + hd] = f2bf(acc[i][nq][r] * sc);
                    }
                }
            }
        }
    } else {
#pragma unroll
        for (int nq = 0; nq < 4; ++nq) {
            int col = cbase + nq * 16;
            float bv = bias[col];
#pragma unroll
            for (int i = 0; i < 8; ++i) {
#pragma unroll
                for (int r = 0; r < 4; ++r) {
                    int row = rbase + i * 16 + r;
                    outF[(size_t)row * DD + col] = acc[i][nq][r] + bv;
                }
            }
        }
    }
}

// ---------------- flash attention: 4 warps x 32 q-rows, KVBLK=64, paired q-tiles --------------
// V LDS layout: 64 rows x 256B, row r = {VT[r][k0..k0+64], VT[r+64][k0..k0+64]}, 4-bit XOR key
// (r&15) -> PV ds_read_b128 is 2-way (free) instead of 4-way. K rows 256B with (row&15) key.
__global__ __launch_bounds__(256, 2) void attn_kernel(
    const unsigned short* __restrict__ Q, const unsigned short* __restrict__ K,
    const unsigned short* __restrict__ VT, unsigned short* __restrict__ ctx) {
    __shared__ __attribute__((aligned(16))) unsigned short Ks[2][64 * 128];
    __shared__ __attribute__((aligned(16))) unsigned short Vs[2][64 * 128];
    __shared__ float Al[4][32];
    const int tid = threadIdx.x, w = tid >> 6, l = tid & 63;
    const int hi = l >> 5, l31 = l & 31;
    const int hb = hi * 16;
    const int swzK = (l31 & 15) << 4;
    const int keyV = l31 & 15;
    const int p = blockIdx.x, h = blockIdx.y, b = blockIdx.z;
    const int bh = b * HH + h;

    const unsigned short* Qbh = Q + (size_t)bh * SS * HDD;
    const char* Kbh = (const char*)(K + (size_t)bh * SS * HDD);
    const char* Vbh = (const char*)(VT + (size_t)bh * HDD * SS);

    const char* kbase[4];
    const char* vbase[4];
#pragma unroll
    for (int i = 0; i < 4; ++i) {
        int chunk = i * 256 + tid;            // 16B chunk index 0..1023
        int krow = chunk >> 4, kslot = chunk & 15;
        kbase[i] = Kbh + (size_t)krow * 256 + ((kslot ^ (krow & 15)) << 4);
        // V: row r holds d=r (slots 0-7) and d=r+64 (slots 8-15), slot XOR (r&15)
        int vr = chunk >> 4, vslot = chunk & 15;
        int g = vslot ^ (vr & 15);
        int half = g >> 3, k16 = g & 7;
        vbase[i] = Vbh + (size_t)(vr + 64 * half) * (SS * 2) + k16 * 16;
    }

    auto stageK = [&](int buf, int kv0) {
#pragma unroll
        for (int i = 0; i < 4; ++i) {
            int cp = (i * 256 + tid) * 16;
            gload_lds16(kbase[i] + (size_t)kv0 * 256, (char*)&Ks[buf][0] + cp);
        }
    };
    auto stageV = [&](int buf, int kv0) {
#pragma unroll
        for (int i = 0; i < 4; ++i) {
            int cp = (i * 256 + tid) * 16;
            gload_lds16(vbase[i] + (size_t)kv0 * 2, (char*)&Vs[buf][0] + cp);
        }
    };

    for (int pass = 0; pass < 2; ++pass) {
        const int qt = pass ? p : 15 - p;
        const int q0w = qt * 128 + w * 32;
        const int qabs = q0w + l31;
        const int nkv = 2 * qt + 2;

        bf16x8_t qf[8];
#pragma unroll
        for (int ds = 0; ds < 8; ++ds)
            qf[ds] = *(const bf16x8_t*)(Qbh + (size_t)qabs * HDD + ds * 16 + hi * 8);

        float m_r = -1e30f, l_r = 0.f;
        f32x16 o0 = {}, o1 = {}, o2 = {}, o3 = {};

        int buf = 0;
        stageK(0, 0);
        stageV(0, 0);
        asm volatile("s_waitcnt vmcnt(4)" ::: "memory");
        __builtin_amdgcn_s_barrier();

        for (int kt = 0; kt < nkv; ++kt) {
            const int kv0 = kt * 64;
            const bool nlast = (kt + 1 < nkv);
            if (nlast) { stageK(buf ^ 1, kv0 + 64); stageV(buf ^ 1, kv0 + 64); }

            const bool active = (kv0 <= q0w + 31);
            const char* Kb = (const char*)&Ks[buf][0];
            const char* Vb = (const char*)&Vs[buf][0];
            f32x16 s0, s1;
            bf16x8_t pa[4];
            if (active) {
                s0 = (f32x16){}; s1 = (f32x16){};
                {
                    bf16x8_t kf[8];
                    const int rb = l31 * 256;
#pragma unroll
                    for (int ds = 0; ds < 8; ++ds)
                        kf[ds] = *(const bf16x8_t*)(Kb + rb + ((ds * 32 + hb) ^ swzK));
                    __builtin_amdgcn_s_setprio(1);
#pragma unroll
                    for (int ds = 0; ds < 8; ++ds)
                        s0 = __builtin_amdgcn_mfma_f32_32x32x16_bf16(kf[ds], qf[ds], s0, 0, 0, 0);
                    __builtin_amdgcn_s_setprio(0);
#pragma unroll
                    for (int ds = 0; ds < 8; ++ds)
                        kf[ds] = *(const bf16x8_t*)(Kb + rb + 32 * 256 + ((ds * 32 + hb) ^ swzK));
                    __builtin_amdgcn_s_setprio(1);
#pragma unroll
                    for (int ds = 0; ds < 8; ++ds)
                        s1 = __builtin_amdgcn_mfma_f32_32x32x16_bf16(kf[ds], qf[ds], s1, 0, 0, 0);
                    __builtin_amdgcn_s_setprio(0);
                }

                if (kv0 + 63 > q0w) {
                    const int qrel = qabs - kv0;
#pragma unroll
                    for (int r = 0; r < 16; ++r) {
                        const int kl = (r & 3) + 8 * (r >> 2) + 4 * hi;
                        if (kl > qrel) s0[r] = -1e30f;
                        if (kl + 32 > qrel) s1[r] = -1e30f;
                    }
                }

                float mx = s0[0];
#pragma unroll
                for (int r = 1; r < 16; ++r) mx = fmaxf(mx, s0[r]);
#pragma unroll
                for (int r = 0; r < 16; ++r) mx = fmaxf(mx, s1[r]);
                {
                    unsigned mu = __float_as_uint(mx), mu2 = mu;
                    pl32swap(mu, mu2);
                    mx = fmaxf(__uint_as_float(mu), __uint_as_float(mu2));
                }

                if (__any(mx - m_r > 8.f)) {
                    float mnew = fmaxf(m_r, mx);
                    float alpha = exp2f(m_r - mnew);
                    m_r = mnew;
                    l_r *= alpha;
                    Al[w][l31] = alpha;
#pragma unroll
                    for (int r = 0; r < 16; ++r) {
                        float ar = Al[w][(r & 3) + 8 * (r >> 2) + 4 * hi];
                        o0[r] *= ar; o1[r] *= ar; o2[r] *= ar; o3[r] *= ar;
                    }
                }

                float ps = 0.f;
#pragma unroll
                for (int r = 0; r < 16; ++r) { s0[r] = exp2f(s0[r] - m_r); ps += s0[r]; }
#pragma unroll
                for (int r = 0; r < 16; ++r) { s1[r] = exp2f(s1[r] - m_r); ps += s1[r]; }
                {
                    unsigned pu = __float_as_uint(ps), pu2 = pu;
                    pl32swap(pu, pu2);
                    l_r += __uint_as_float(pu) + __uint_as_float(pu2);
                }

                {
                    union { unsigned u[4]; bf16x8_t v; } uu;
#define MK_PA(SV, BASE, OUT)                                     \
                    {                                            \
                        unsigned X0 = cvtpk_bf16(SV[BASE + 0], SV[BASE + 1]); \
                        unsigned Y0 = cvtpk_bf16(SV[BASE + 4], SV[BASE + 5]); \
                        pl32swap(X0, Y0);                        \
                        unsigned X1 = cvtpk_bf16(SV[BASE + 2], SV[BASE + 3]); \
                        unsigned Y1 = cvtpk_bf16(SV[BASE + 6], SV[BASE + 7]); \
                        pl32swap(X1, Y1);                        \
                        uu.u[0] = X0; uu.u[1] = X1; uu.u[2] = Y0; uu.u[3] = Y1; \
                        OUT = uu.v;                              \
                    }
                    MK_PA(s0, 0, pa[0]);
                    MK_PA(s0, 8, pa[1]);
                    MK_PA(s1, 0, pa[2]);
                    MK_PA(s1, 8, pa[3]);
#undef MK_PA
                }
            }

            if (nlast) { asm volatile("s_waitcnt vmcnt(8)" ::: "memory"); }
            else       { asm volatile("s_waitcnt vmcnt(0)" ::: "memory"); }
            __builtin_amdgcn_s_barrier();

            if (active) {
#pragma unroll
                for (int ks = 0; ks < 4; ++ks) {
                    bf16x8_t vf[4];
#pragma unroll
                    for (int dsub = 0; dsub < 4; ++dsub) {
                        int vr = (dsub & 1) * 32 + l31;
                        int c = (dsub >> 1) * 8 + ks * 2 + hi;
                        vf[dsub] = *(const bf16x8_t*)(Vb + vr * 256 + ((c ^ keyV) << 4));
                    }
                    __builtin_amdgcn_s_setprio(1);
                    o0 = __builtin_amdgcn_mfma_f32_32x32x16_bf16(pa[ks], vf[0], o0, 0, 0, 0);
                    o1 = __builtin_amdgcn_mfma_f32_32x32x16_bf16(pa[ks], vf[1], o1, 0, 0, 0);
                    o2 = __builtin_amdgcn_mfma_f32_32x32x16_bf16(pa[ks], vf[2], o2, 0, 0, 0);
                    o3 = __builtin_amdgcn_mfma_f32_32x32x16_bf16(pa[ks], vf[3], o3, 0, 0, 0);
                    __builtin_amdgcn_s_setprio(0);
                }
            }

            if (nlast) { asm volatile("s_waitcnt vmcnt(4)" ::: "memory"); }
            __builtin_amdgcn_s_barrier();
            buf ^= 1;
        }

        Al[w][l31] = 1.f / l_r;
        unsigned short* cb_ = ctx + (size_t)b * SS * DD + (size_t)h * HDD;
#pragma unroll
        for (int r = 0; r < 16; ++r) {
            const int ql = (r & 3) + 8 * (r >> 2) + 4 * hi;
            float inv = Al[w][ql];
            const size_t rowoff = (size_t)(q0w + ql) * DD;
            cb_[rowoff + 0 * 32 + l31] = f2bf(o0[r] * inv);
            cb_[rowoff + 1 * 32 + l31] = f2bf(o1[r] * inv);
            cb_[rowoff + 2 * 32 + l31] = f2bf(o2[r] * inv);
            cb_[rowoff + 3 * 32 + l31] = f2bf(o3[r] * inv);
        }
        __syncthreads();
    }
}

extern "C" void kernel_launch(void* const* d_in, const int* in_sizes, int n_in,
                              void* d_out, int out_size, void* d_ws, size_t ws_size,
                              hipStream_t stream) {
    (void)in_sizes; (void)n_in; (void)out_size; (void)ws_size;
    const float* x  = (const float*)d_in[0];
    const float* Wq = (const float*)d_in[1];
    const float* Wk = (const float*)d_in[2];
    const float* Wv = (const float*)d_in[3];
    const float* Wo = (const float*)d_in[4];
    const float* bo = (const float*)d_in[5];

    char* ws = (char*)d_ws;
    unsigned short* xb    = (unsigned short*)(ws);
    unsigned short* WqkvT = (unsigned short*)(ws + (32u << 20));
    unsigned short* WoT   = (unsigned short*)(ws + (56u << 20));
    unsigned short* Qb    = (unsigned short*)(ws + (64u << 20));
    unsigned short* Kb    = (unsigned short*)(ws + (96u << 20));
    unsigned short* VTb   = (unsigned short*)(ws + (160u << 20));
    unsigned short* ctx   = xb;  // xb dead after QKV GEMM

    convert_x<<<4096, 256, 0, stream>>>(x, xb, BB * SS * DD);
    transpose_w<<<dim3(64, 64, 4), dim3(32, 8), 0, stream>>>(Wq, Wk, Wv, Wo, WqkvT, WoT);
    gemm256<0><<<dim3(24, 32), 512, 0, stream>>>(xb, WqkvT, Qb, Kb, VTb, nullptr, nullptr);
    attn_kernel<<<dim3(8, HH, BB), 256, 0, stream>>>(Qb, Kb, VTb, ctx);
    gemm256<1><<<dim3(8, 32), 512, 0, stream>>>(ctx, WoT, nullptr, nullptr, nullptr, (float*)d_out, bo);
}

// Round 14
// 418.155 us; speedup vs baseline: 1.0223x; 1.0207x over previous
//
#include <hip/hip_runtime.h>
#include <hip/hip_bf16.h>

#define BB 4
#define SS 2048
#define DD 2048
#define HH 16
#define HDD 128

typedef __bf16 bf16x8_t __attribute__((ext_vector_type(8)));
typedef float f32x4 __attribute__((ext_vector_type(4)));
typedef float f32x16 __attribute__((ext_vector_type(16)));
typedef unsigned short us8 __attribute__((ext_vector_type(8)));

static __device__ __forceinline__ unsigned short f2bf(float f) {
    union { float f; unsigned u; } v; v.f = f;
    unsigned r = v.u + 0x7fffu + ((v.u >> 16) & 1u);
    return (unsigned short)(r >> 16);
}

static __device__ __forceinline__ unsigned cvtpk_bf16(float lo, float hiv) {
    unsigned r;
    asm("v_cvt_pk_bf16_f32 %0, %1, %2" : "=v"(r) : "v"(lo), "v"(hiv));
    return r;
}

static __device__ __forceinline__ void pl32swap(unsigned& a, unsigned& b) {
    auto rr = __builtin_amdgcn_permlane32_swap((int)a, (int)b, false, false);
    a = (unsigned)rr[0];
    b = (unsigned)rr[1];
}

static __device__ __forceinline__ void gload_lds16(const void* g, void* lds) {
    __builtin_amdgcn_global_load_lds(
        (const __attribute__((address_space(1))) void*)g,
        (__attribute__((address_space(3))) void*)lds, 16, 0, 0);
}

// ---------------- convert x fp32 -> bf16 ----------------
__global__ void convert_x(const float* __restrict__ x, unsigned short* __restrict__ xb, int n) {
    int i = (blockIdx.x * blockDim.x + threadIdx.x) * 4;
    int stride = gridDim.x * blockDim.x * 4;
    for (; i < n; i += stride) {
        float4 v = *(const float4*)(x + i);
        ushort4 o;
        o.x = f2bf(v.x); o.y = f2bf(v.y); o.z = f2bf(v.z); o.w = f2bf(v.w);
        *(ushort4*)(xb + i) = o;
    }
}

// ---------------- transpose + convert weights: T[n][k] = W[k][n] ----------------
__global__ void transpose_w(const float* __restrict__ Wq, const float* __restrict__ Wk,
                            const float* __restrict__ Wv, const float* __restrict__ Wo,
                            unsigned short* __restrict__ WqkvT, unsigned short* __restrict__ WoT) {
    __shared__ float t[32][33];
    const int z = blockIdx.z;
    const float* W = (z == 0) ? Wq : (z == 1) ? Wk : (z == 2) ? Wv : Wo;
    unsigned short* T = (z < 3) ? (WqkvT + (size_t)z * DD * DD) : WoT;
    const int k0 = blockIdx.x * 32, n0 = blockIdx.y * 32;
    const int tx = threadIdx.x, ty = threadIdx.y;
#pragma unroll
    for (int i = 0; i < 4; ++i) {
        int r = ty + i * 8;
        t[r][tx] = W[(size_t)(k0 + r) * DD + n0 + tx];
    }
    __syncthreads();
#pragma unroll
    for (int i = 0; i < 4; ++i) {
        int r = ty + i * 8;
        T[(size_t)(n0 + r) * DD + k0 + tx] = f2bf(t[tx][r]);
    }
}

// ---------------- 256x256 GEMM, BK=64, 8 waves, per-phase interleave; LDS-bounce epilogue ------
// MODE 0: Q pre-scaled by softmax scale*log2(e); Q,K -> [bh][s][hd]; V -> VT [bh][hd][s].
// Epilogue bounces acc through LDS (dead after K-loop) for coalesced 16B/lane stores.
template <int MODE>
__global__ __launch_bounds__(512, 1) void gemm256(
    const unsigned short* __restrict__ A, const unsigned short* __restrict__ BT,
    unsigned short* __restrict__ outQ, unsigned short* __restrict__ outK,
    unsigned short* __restrict__ outV, float* __restrict__ outF,
    const float* __restrict__ bias) {
    __shared__ __attribute__((aligned(16))) char lds[131072];
    const int tid = threadIdx.x, l = tid & 63;
    const int w = tid >> 6;
    const int wr = w >> 2, wc = w & 3;
    const int nwg = gridDim.x * gridDim.y;
    int lin = blockIdx.y * gridDim.x + blockIdx.x;
    lin = (lin & 7) * (nwg >> 3) + (lin >> 3);
    const int m0 = (lin / gridDim.x) * 256;
    const int n0 = (lin % gridDim.x) * 256;

    f32x4 acc[8][4] = {};

    const int rowl = tid >> 3, c16s = tid & 7;
    const int sw16 = (c16s ^ (rowl & 7)) * 16;
    const char* aSrc[4];
    const char* bSrc[4];
#pragma unroll
    for (int rg = 0; rg < 4; ++rg) {
        aSrc[rg] = (const char*)A + ((size_t)(m0 + rg * 64 + rowl) * 2048) * 2 + sw16;
        bSrc[rg] = (const char*)BT + ((size_t)(n0 + rg * 64 + rowl) * 2048) * 2 + sw16;
    }
    const int dstOff = tid * 16;

    auto stage2 = [&](int slot, int off, int which) {
        char* sA = lds + slot * 32768;
        char* sB = lds + 65536 + slot * 32768;
        if (which == 0) { gload_lds16(bSrc[0] + off, sB + 0 * 8192 + dstOff); gload_lds16(bSrc[1] + off, sB + 1 * 8192 + dstOff); }
        else if (which == 1) { gload_lds16(bSrc[2] + off, sB + 2 * 8192 + dstOff); gload_lds16(bSrc[3] + off, sB + 3 * 8192 + dstOff); }
        else if (which == 2) { gload_lds16(aSrc[0] + off, sA + 0 * 8192 + dstOff); gload_lds16(aSrc[2] + off, sA + 2 * 8192 + dstOff); }
        else { gload_lds16(aSrc[1] + off, sA + 1 * 8192 + dstOff); gload_lds16(aSrc[3] + off, sA + 3 * 8192 + dstOff); }
    };

#pragma unroll
    for (int q = 0; q < 4; ++q) stage2(0, 0, q);
    asm volatile("s_waitcnt vmcnt(0)" ::: "memory");
    __builtin_amdgcn_s_barrier();

    const int lr = l & 15, hi4 = l >> 4;
    for (int t = 0; t < 32; ++t) {
        const int cur = t & 1, sl1 = cur ^ 1;
        const bool nlast = (t + 1 < 32);
        const int off1 = (t + 1) * 128;
        const char* As_ = lds + cur * 32768;
        const char* Bs_ = lds + 65536 + cur * 32768;
        bf16x8_t aa[4], bb[4];

        // ---- p0: (mh0, k0) ----
#pragma unroll
        for (int mq = 0; mq < 4; ++mq) {
            int row = wr * 128 + mq * 16 + lr;
            aa[mq] = *(const bf16x8_t*)(As_ + row * 128 + ((hi4) ^ (row & 7)) * 16);
        }
#pragma unroll
        for (int nq = 0; nq < 4; ++nq) {
            int col = wc * 64 + nq * 16 + lr;
            bb[nq] = *(const bf16x8_t*)(Bs_ + col * 128 + ((hi4) ^ (col & 7)) * 16);
        }
        if (nlast) stage2(sl1, off1, 0);
        __builtin_amdgcn_s_barrier();
        asm volatile("s_waitcnt lgkmcnt(0)");
        __builtin_amdgcn_s_setprio(1);
#pragma unroll
        for (int mq = 0; mq < 4; ++mq)
#pragma unroll
            for (int nq = 0; nq < 4; ++nq)
                acc[mq][nq] = __builtin_amdgcn_mfma_f32_16x16x32_bf16(aa[mq], bb[nq], acc[mq][nq], 0, 0, 0);
        __builtin_amdgcn_s_setprio(0);
        if (nlast) { asm volatile("s_waitcnt vmcnt(2)" ::: "memory"); }
        else       { asm volatile("s_waitcnt vmcnt(0)" ::: "memory"); }
        __builtin_amdgcn_s_barrier();

        // ---- p1: (mh1, k0), bb reused ----
#pragma unroll
        for (int mq = 0; mq < 4; ++mq) {
            int row = wr * 128 + 64 + mq * 16 + lr;
            aa[mq] = *(const bf16x8_t*)(As_ + row * 128 + ((hi4) ^ (row & 7)) * 16);
        }
        if (nlast) stage2(sl1, off1, 1);
        __builtin_amdgcn_s_barrier();
        asm volatile("s_waitcnt lgkmcnt(0)");
        __builtin_amdgcn_s_setprio(1);
#pragma unroll
        for (int mq = 0; mq < 4; ++mq)
#pragma unroll
            for (int nq = 0; nq < 4; ++nq)
                acc[4 + mq][nq] = __builtin_amdgcn_mfma_f32_16x16x32_bf16(aa[mq], bb[nq], acc[4 + mq][nq], 0, 0, 0);
        __builtin_amdgcn_s_setprio(0);
        __builtin_amdgcn_s_barrier();

        // ---- p2: (mh0, k1) ----
#pragma unroll
        for (int mq = 0; mq < 4; ++mq) {
            int row = wr * 128 + mq * 16 + lr;
            aa[mq] = *(const bf16x8_t*)(As_ + row * 128 + ((4 + hi4) ^ (row & 7)) * 16);
        }
#pragma unroll
        for (int nq = 0; nq < 4; ++nq) {
            int col = wc * 64 + nq * 16 + lr;
            bb[nq] = *(const bf16x8_t*)(Bs_ + col * 128 + ((4 + hi4) ^ (col & 7)) * 16);
        }
        if (nlast) stage2(sl1, off1, 2);
        __builtin_amdgcn_s_barrier();
        asm volatile("s_waitcnt lgkmcnt(0)");
        __builtin_amdgcn_s_setprio(1);
#pragma unroll
        for (int mq = 0; mq < 4; ++mq)
#pragma unroll
            for (int nq = 0; nq < 4; ++nq)
                acc[mq][nq] = __builtin_amdgcn_mfma_f32_16x16x32_bf16(aa[mq], bb[nq], acc[mq][nq], 0, 0, 0);
        __builtin_amdgcn_s_setprio(0);
        __builtin_amdgcn_s_barrier();

        // ---- p3: (mh1, k1), bb reused ----
#pragma unroll
        for (int mq = 0; mq < 4; ++mq) {
            int row = wr * 128 + 64 + mq * 16 + lr;
            aa[mq] = *(const bf16x8_t*)(As_ + row * 128 + ((4 + hi4) ^ (row & 7)) * 16);
        }
        if (nlast) stage2(sl1, off1, 3);
        __builtin_amdgcn_s_barrier();
        asm volatile("s_waitcnt lgkmcnt(0)");
        __builtin_amdgcn_s_setprio(1);
#pragma unroll
        for (int mq = 0; mq < 4; ++mq)
#pragma unroll
            for (int nq = 0; nq < 4; ++nq)
                acc[4 + mq][nq] = __builtin_amdgcn_mfma_f32_16x16x32_bf16(aa[mq], bb[nq], acc[4 + mq][nq], 0, 0, 0);
        __builtin_amdgcn_s_setprio(0);
        if (nlast) { asm volatile("s_waitcnt vmcnt(2)" ::: "memory"); }
        __builtin_amdgcn_s_barrier();
    }

    // ---- epilogue: LDS-bounce for coalesced stores ----
    const int b_ = m0 >> 11, s0_ = m0 & 2047;
    if (MODE == 0) {
        const float QSCALE = 0.08838834764831845f * 1.4426950408889634f;
        const int mat = n0 >> 11;
        const int nn0 = n0 & 2047;
        const int h0 = nn0 >> 7;  // 2 heads per 256-col block
        if (mat < 2) {
            unsigned short* outp = mat ? outK : outQ;
            const float sc = mat ? 1.f : QSCALE;
            unsigned short* L = (unsigned short*)lds;
            // two halves of 128 s-rows; LDS [128 s][264 shorts (256 cols + pad)]
            for (int half = 0; half < 2; ++half) {
                __builtin_amdgcn_s_barrier();
                if (wr == half) {
#pragma unroll
                    for (int i = 0; i < 8; ++i)
#pragma unroll
                        for (int nq = 0; nq < 4; ++nq)
#pragma unroll
                            for (int r = 0; r < 4; ++r) {
                                int srow = i * 16 + (hi4 << 2) + r;
                                int col = wc * 64 + nq * 16 + lr;
                                L[srow * 264 + col] = f2bf(acc[i][nq][r] * sc);
                            }
                }
                __builtin_amdgcn_s_barrier();
#pragma unroll
                for (int it = 0; it < 8; ++it) {
                    int id = it * 512 + tid;
                    int srow = id >> 5, c16 = id & 31;
                    int h = h0 + (c16 >> 4), hd8 = (c16 & 15) * 8;
                    us8 v = *(const us8*)(L + srow * 264 + c16 * 8);
                    unsigned short* gp = outp +
                        (((size_t)(b_ * HH + h)) * SS + (s0_ + half * 128 + srow)) * HDD + hd8;
                    *(us8*)gp = v;
                }
            }
        } else {
            // V: per head (halfc), LDS col-major [128 hd][264 shorts (256 s + pad)]
            unsigned short* L = (unsigned short*)lds;
            for (int halfc = 0; halfc < 2; ++halfc) {
                __builtin_amdgcn_s_barrier();
                if ((wc >> 1) == halfc) {
#pragma unroll
                    for (int i = 0; i < 8; ++i)
#pragma unroll
                        for (int nq = 0; nq < 4; ++nq) {
                            int lcol = (wc & 1) * 64 + nq * 16 + lr;
                            int sbase = wr * 128 + i * 16 + (hi4 << 2);
                            ushort4 pk;
                            pk.x = f2bf(acc[i][nq][0]); pk.y = f2bf(acc[i][nq][1]);
                            pk.z = f2bf(acc[i][nq][2]); pk.w = f2bf(acc[i][nq][3]);
                            *(ushort4*)(L + lcol * 264 + sbase) = pk;
                        }
                }
                __builtin_amdgcn_s_barrier();
#pragma unroll
                for (int it = 0; it < 8; ++it) {
                    int id = it * 512 + tid;
                    int lcol = id >> 5, s16 = id & 31;
                    us8 v = *(const us8*)(L + lcol * 264 + s16 * 8);
                    unsigned short* gp = outV +
                        ((size_t)(b_ * HH + h0 + halfc) * HDD + lcol) * SS + s0_ + s16 * 8;
                    *(us8*)gp = v;
                }
            }
        }
    } else {
        // fp32 out + bias: quarters of 64 rows; LDS [64 rows][260 floats (256 + pad)]
        float* L = (float*)lds;
        float bv[4];
#pragma unroll
        for (int nq = 0; nq < 4; ++nq) bv[nq] = bias[n0 + wc * 64 + nq * 16 + lr];
        for (int qtr = 0; qtr < 4; ++qtr) {
            __builtin_amdgcn_s_barrier();
            if (wr == (qtr >> 1)) {
#pragma unroll
                for (int ii = 0; ii < 4; ++ii) {
                    int i = (qtr & 1) * 4 + ii;
#pragma unroll
                    for (int nq = 0; nq < 4; ++nq)
#pragma unroll
                        for (int r = 0; r < 4; ++r) {
                            int lrow = ii * 16 + (hi4 << 2) + r;
                            int col = wc * 64 + nq * 16 + lr;
                            L[lrow * 260 + col] = acc[i][nq][r] + bv[nq];
                        }
                }
            }
            __builtin_amdgcn_s_barrier();
#pragma unroll
            for (int it = 0; it < 8; ++it) {
                int id = it * 512 + tid;
                int lrow = id >> 6, c4 = (id & 63) * 4;
                float4 v = *(const float4*)(L + lrow * 260 + c4);
                *(float4*)(outF + (size_t)(m0 + qtr * 64 + lrow) * DD + n0 + c4) = v;
            }
        }
    }
}

// ---------------- flash attention: 4 warps x 32 q-rows, KVBLK=64, paired q-tiles (R13) --------
__global__ __launch_bounds__(256, 2) void attn_kernel(
    const unsigned short* __restrict__ Q, const unsigned short* __restrict__ K,
    const unsigned short* __restrict__ VT, unsigned short* __restrict__ ctx) {
    __shared__ __attribute__((aligned(16))) unsigned short Ks[2][64 * 128];
    __shared__ __attribute__((aligned(16))) unsigned short Vs[2][64 * 128];
    __shared__ float Al[4][32];
    const int tid = threadIdx.x, w = tid >> 6, l = tid & 63;
    const int hi = l >> 5, l31 = l & 31;
    const int hb = hi * 16;
    const int swzK = (l31 & 15) << 4;
    const int keyV = l31 & 15;
    const int p = blockIdx.x, h = blockIdx.y, b = blockIdx.z;
    const int bh = b * HH + h;

    const unsigned short* Qbh = Q + (size_t)bh * SS * HDD;
    const char* Kbh = (const char*)(K + (size_t)bh * SS * HDD);
    const char* Vbh = (const char*)(VT + (size_t)bh * HDD * SS);

    const char* kbase[4];
    const char* vbase[4];
#pragma unroll
    for (int i = 0; i < 4; ++i) {
        int chunk = i * 256 + tid;
        int krow = chunk >> 4, kslot = chunk & 15;
        kbase[i] = Kbh + (size_t)krow * 256 + ((kslot ^ (krow & 15)) << 4);
        int vr = chunk >> 4, vslot = chunk & 15;
        int g = vslot ^ (vr & 15);
        int half = g >> 3, k16 = g & 7;
        vbase[i] = Vbh + (size_t)(vr + 64 * half) * (SS * 2) + k16 * 16;
    }

    auto stageK = [&](int buf, int kv0) {
#pragma unroll
        for (int i = 0; i < 4; ++i) {
            int cp = (i * 256 + tid) * 16;
            gload_lds16(kbase[i] + (size_t)kv0 * 256, (char*)&Ks[buf][0] + cp);
        }
    };
    auto stageV = [&](int buf, int kv0) {
#pragma unroll
        for (int i = 0; i < 4; ++i) {
            int cp = (i * 256 + tid) * 16;
            gload_lds16(vbase[i] + (size_t)kv0 * 2, (char*)&Vs[buf][0] + cp);
        }
    };

    for (int pass = 0; pass < 2; ++pass) {
        const int qt = pass ? p : 15 - p;
        const int q0w = qt * 128 + w * 32;
        const int qabs = q0w + l31;
        const int nkv = 2 * qt + 2;

        bf16x8_t qf[8];
#pragma unroll
        for (int ds = 0; ds < 8; ++ds)
            qf[ds] = *(const bf16x8_t*)(Qbh + (size_t)qabs * HDD + ds * 16 + hi * 8);

        float m_r = -1e30f, l_r = 0.f;
        f32x16 o0 = {}, o1 = {}, o2 = {}, o3 = {};

        int buf = 0;
        stageK(0, 0);
        stageV(0, 0);
        asm volatile("s_waitcnt vmcnt(4)" ::: "memory");
        __builtin_amdgcn_s_barrier();

        for (int kt = 0; kt < nkv; ++kt) {
            const int kv0 = kt * 64;
            const bool nlast = (kt + 1 < nkv);
            if (nlast) { stageK(buf ^ 1, kv0 + 64); stageV(buf ^ 1, kv0 + 64); }

            const bool active = (kv0 <= q0w + 31);
            const char* Kb = (const char*)&Ks[buf][0];
            const char* Vb = (const char*)&Vs[buf][0];
            f32x16 s0, s1;
            bf16x8_t pa[4];
            if (active) {
                s0 = (f32x16){}; s1 = (f32x16){};
                {
                    bf16x8_t kf[8];
                    const int rb = l31 * 256;
#pragma unroll
                    for (int ds = 0; ds < 8; ++ds)
                        kf[ds] = *(const bf16x8_t*)(Kb + rb + ((ds * 32 + hb) ^ swzK));
                    __builtin_amdgcn_s_setprio(1);
#pragma unroll
                    for (int ds = 0; ds < 8; ++ds)
                        s0 = __builtin_amdgcn_mfma_f32_32x32x16_bf16(kf[ds], qf[ds], s0, 0, 0, 0);
                    __builtin_amdgcn_s_setprio(0);
#pragma unroll
                    for (int ds = 0; ds < 8; ++ds)
                        kf[ds] = *(const bf16x8_t*)(Kb + rb + 32 * 256 + ((ds * 32 + hb) ^ swzK));
                    __builtin_amdgcn_s_setprio(1);
#pragma unroll
                    for (int ds = 0; ds < 8; ++ds)
                        s1 = __builtin_amdgcn_mfma_f32_32x32x16_bf16(kf[ds], qf[ds], s1, 0, 0, 0);
                    __builtin_amdgcn_s_setprio(0);
                }

                if (kv0 + 63 > q0w) {
                    const int qrel = qabs - kv0;
#pragma unroll
                    for (int r = 0; r < 16; ++r) {
                        const int kl = (r & 3) + 8 * (r >> 2) + 4 * hi;
                        if (kl > qrel) s0[r] = -1e30f;
                        if (kl + 32 > qrel) s1[r] = -1e30f;
                    }
                }

                float mx = s0[0];
#pragma unroll
                for (int r = 1; r < 16; ++r) mx = fmaxf(mx, s0[r]);
#pragma unroll
                for (int r = 0; r < 16; ++r) mx = fmaxf(mx, s1[r]);
                {
                    unsigned mu = __float_as_uint(mx), mu2 = mu;
                    pl32swap(mu, mu2);
                    mx = fmaxf(__uint_as_float(mu), __uint_as_float(mu2));
                }

                if (__any(mx - m_r > 8.f)) {
                    float mnew = fmaxf(m_r, mx);
                    float alpha = exp2f(m_r - mnew);
                    m_r = mnew;
                    l_r *= alpha;
                    Al[w][l31] = alpha;
#pragma unroll
                    for (int r = 0; r < 16; ++r) {
                        float ar = Al[w][(r & 3) + 8 * (r >> 2) + 4 * hi];
                        o0[r] *= ar; o1[r] *= ar; o2[r] *= ar; o3[r] *= ar;
                    }
                }

                float ps = 0.f;
#pragma unroll
                for (int r = 0; r < 16; ++r) { s0[r] = exp2f(s0[r] - m_r); ps += s0[r]; }
#pragma unroll
                for (int r = 0; r < 16; ++r) { s1[r] = exp2f(s1[r] - m_r); ps += s1[r]; }
                {
                    unsigned pu = __float_as_uint(ps), pu2 = pu;
                    pl32swap(pu, pu2);
                    l_r += __uint_as_float(pu) + __uint_as_float(pu2);
                }

                {
                    union { unsigned u[4]; bf16x8_t v; } uu;
#define MK_PA(SV, BASE, OUT)                                     \
                    {                                            \
                        unsigned X0 = cvtpk_bf16(SV[BASE + 0], SV[BASE + 1]); \
                        unsigned Y0 = cvtpk_bf16(SV[BASE + 4], SV[BASE + 5]); \
                        pl32swap(X0, Y0);                        \
                        unsigned X1 = cvtpk_bf16(SV[BASE + 2], SV[BASE + 3]); \
                        unsigned Y1 = cvtpk_bf16(SV[BASE + 6], SV[BASE + 7]); \
                        pl32swap(X1, Y1);                        \
                        uu.u[0] = X0; uu.u[1] = X1; uu.u[2] = Y0; uu.u[3] = Y1; \
                        OUT = uu.v;                              \
                    }
                    MK_PA(s0, 0, pa[0]);
                    MK_PA(s0, 8, pa[1]);
                    MK_PA(s1, 0, pa[2]);
                    MK_PA(s1, 8, pa[3]);
#undef MK_PA
                }
            }

            if (nlast) { asm volatile("s_waitcnt vmcnt(8)" ::: "memory"); }
            else       { asm volatile("s_waitcnt vmcnt(0)" ::: "memory"); }
            __builtin_amdgcn_s_barrier();

            if (active) {
#pragma unroll
                for (int ks = 0; ks < 4; ++ks) {
                    bf16x8_t vf[4];
#pragma unroll
                    for (int dsub = 0; dsub < 4; ++dsub) {
                        int vr = (dsub & 1) * 32 + l31;
                        int c = (dsub >> 1) * 8 + ks * 2 + hi;
                        vf[dsub] = *(const bf16x8_t*)(Vb + vr * 256 + ((c ^ keyV) << 4));
                    }
                    __builtin_amdgcn_s_setprio(1);
                    o0 = __builtin_amdgcn_mfma_f32_32x32x16_bf16(pa[ks], vf[0], o0, 0, 0, 0);
                    o1 = __builtin_amdgcn_mfma_f32_32x32x16_bf16(pa[ks], vf[1], o1, 0, 0, 0);
                    o2 = __builtin_amdgcn_mfma_f32_32x32x16_bf16(pa[ks], vf[2], o2, 0, 0, 0);
                    o3 = __builtin_amdgcn_mfma_f32_32x32x16_bf16(pa[ks], vf[3], o3, 0, 0, 0);
                    __builtin_amdgcn_s_setprio(0);
                }
            }

            if (nlast) { asm volatile("s_waitcnt vmcnt(4)" ::: "memory"); }
            __builtin_amdgcn_s_barrier();
            buf ^= 1;
        }

        Al[w][l31] = 1.f / l_r;
        unsigned short* cb_ = ctx + (size_t)b * SS * DD + (size_t)h * HDD;
#pragma unroll
        for (int r = 0; r < 16; ++r) {
            const int ql = (r & 3) + 8 * (r >> 2) + 4 * hi;
            float inv = Al[w][ql];
            const size_t rowoff = (size_t)(q0w + ql) * DD;
            cb_[rowoff + 0 * 32 + l31] = f2bf(o0[r] * inv);
            cb_[rowoff + 1 * 32 + l31] = f2bf(o1[r] * inv);
            cb_[rowoff + 2 * 32 + l31] = f2bf(o2[r] * inv);
            cb_[rowoff + 3 * 32 + l31] = f2bf(o3[r] * inv);
        }
        __syncthreads();
    }
}

extern "C" void kernel_launch(void* const* d_in, const int* in_sizes, int n_in,
                              void* d_out, int out_size, void* d_ws, size_t ws_size,
                              hipStream_t stream) {
    (void)in_sizes; (void)n_in; (void)out_size; (void)ws_size;
    const float* x  = (const float*)d_in[0];
    const float* Wq = (const float*)d_in[1];
    const float* Wk = (const float*)d_in[2];
    const float* Wv = (const float*)d_in[3];
    const float* Wo = (const float*)d_in[4];
    const float* bo = (const float*)d_in[5];

    char* ws = (char*)d_ws;
    unsigned short* xb    = (unsigned short*)(ws);
    unsigned short* WqkvT = (unsigned short*)(ws + (32u << 20));
    unsigned short* WoT   = (unsigned short*)(ws + (56u << 20));
    unsigned short* Qb    = (unsigned short*)(ws + (64u << 20));
    unsigned short* Kb    = (unsigned short*)(ws + (96u << 20));
    unsigned short* VTb   = (unsigned short*)(ws + (160u << 20));
    unsigned short* ctx   = xb;  // xb dead after QKV GEMM

    convert_x<<<4096, 256, 0, stream>>>(x, xb, BB * SS * DD);
    transpose_w<<<dim3(64, 64, 4), dim3(32, 8), 0, stream>>>(Wq, Wk, Wv, Wo, WqkvT, WoT);
    gemm256<0><<<dim3(24, 32), 512, 0, stream>>>(xb, WqkvT, Qb, Kb, VTb, nullptr, nullptr);
    attn_kernel<<<dim3(8, HH, BB), 256, 0, stream>>>(Qb, Kb, VTb, ctx);
    gemm256<1><<<dim3(8, 32), 512, 0, stream>>>(ctx, WoT, nullptr, nullptr, nullptr, (float*)d_out, bo);
}